// Round 2
// baseline (151.106 us; speedup 1.0000x reference)
//
#include <hip/hip_runtime.h>

// KAN conv (8x1x384x384 f32) -> out (8x1x384x384 f32)
// Algebraic collapse: out[p] = rb + sum_{e in 5x5} sum_{f in 9} Wc[f][e] * F[f][p+e]
// F = (silu(x), bspline_0..7(x)) per source pixel; border corrected separately.

#define HW 384
#define NIMG 8
#define NPX (NIMG * HW * HW)

#define TW 64
#define TH 16
#define FROWS (TH + 4)        // 20
#define FCOLS (TW + 8)        // 72
#define FPOS (FROWS * FCOLS)  // 1440

// extended knot grid g[i] = (i-3)*0.4 - 1.0, i = 0..11 (bit-identical to jnp arange*0.4f-1)
__host__ __device__ constexpr float gkf(int i) { return (float)(i - 3) * 0.4f - 1.0f; }

// Cox-de Boor recursion, verbatim structure of the reference (11 -> 10 -> 9 -> 8)
__device__ __forceinline__ void kan_feats(float x, float f[9]) {
  float b[11];
#pragma unroll
  for (int i = 0; i < 11; ++i)
    b[i] = (x >= gkf(i) && x < gkf(i + 1)) ? 1.0f : 0.0f;
#pragma unroll
  for (int k = 1; k <= 3; ++k) {
#pragma unroll
    for (int i = 0; i < 11 - k; ++i) {
      float lc = (x - gkf(i)) * (1.0f / (gkf(i + k) - gkf(i)));
      float rc = (gkf(i + k + 1) - x) * (1.0f / (gkf(i + k + 1) - gkf(i + 1)));
      b[i] = lc * b[i] + rc * b[i + 1];
    }
  }
  // sigmoid via v_exp + v_rcp (approx rcp: ~1 ulp, fine for f32 tolerance);
  // avoids the exact-division v_div_scale/fmas/fixup sequence (~10 instrs).
  float sg = __builtin_amdgcn_rcpf(1.0f + __expf(-x));
  f[0] = x * sg;  // silu
#pragma unroll
  for (int i = 0; i < 8; ++i) f[1 + i] = b[i];
}

// ---------------- weights prep: Wc[9][5][5] at ws[0..224], h[81][9] at ws[256..984]
__global__ void kan_weights(const float* __restrict__ bw, const float* __restrict__ sw,
                            const float* __restrict__ ss, const float* __restrict__ rw,
                            float* __restrict__ ws) {
  int tid = threadIdx.x;  // 1024 threads, 1 block
  if (tid < 225) {
    int f = tid / 25, e = tid % 25;
    int ey = e / 5 - 2, ex = e % 5 - 2;
    float acc = 0.f;
    for (int dy = -1; dy <= 1; ++dy)
      for (int dx = -1; dx <= 1; ++dx) {
        int ky = ey - dy, kx = ex - dx;
        if (ky < -1 || ky > 1 || kx < -1 || kx > 1) continue;
        int d = (dy + 1) * 3 + dx + 1, k = (ky + 1) * 3 + kx + 1;
        for (int c = 0; c < 16; ++c) {
          float wfv = (f == 0) ? bw[c * 9 + k]
                               : sw[(c * 9 + k) * 8 + (f - 1)] * ss[c * 9 + k];
          acc = fmaf(rw[c * 9 + d], wfv, acc);
        }
      }
    ws[tid] = acc;
  } else if (tid < 225 + 729) {
    int idx = tid - 225;
    int dk = idx / 9, f = idx % 9;
    int d = dk / 9, k = dk % 9;
    float acc = 0.f;
    for (int c = 0; c < 16; ++c) {
      float wfv = (f == 0) ? bw[c * 9 + k]
                           : sw[(c * 9 + k) * 8 + (f - 1)] * ss[c * 9 + k];
      acc = fmaf(rw[c * 9 + d], wfv, acc);
    }
    ws[256 + idx] = acc;
  }
}

// ---------------- main fused kernel: F-tile in LDS + 25-tap stencil
// LDS 51840 B -> 3 blocks/CU (6 waves). Stage-2 model: LDS-instr-bound ~2:1 vs VALU.
__launch_bounds__(128)
__global__ void kan_main(const float* __restrict__ x, const float* __restrict__ Wc,
                         const float* __restrict__ rbp, float* __restrict__ out) {
  __shared__ __align__(16) float Fp[9][FPOS];  // planar per-feature, stride 72 floats
  const int tx0 = blockIdx.x * TW, ty0 = blockIdx.y * TH, img = blockIdx.z;
  const float* xim = x + img * HW * HW;
  const int tid = threadIdx.y * 16 + threadIdx.x;

  // stage 1: F records for the halo'd tile (rows -2..17, cols -4..67)
#pragma unroll
  for (int it = 0; it < 12; ++it) {
    int id = it * 128 + tid;
    if (id < FPOS) {
      int r = id / FCOLS, cl = id - r * FCOLS;
      int row = ty0 + r - 2, col = tx0 + cl - 4;
      float v = (row >= 0 && row < HW && col >= 0 && col < HW) ? xim[row * HW + col] : 0.0f;
      float f[9];
      kan_feats(v, f);
#pragma unroll
      for (int ft = 0; ft < 9; ++ft) Fp[ft][id] = f[ft];
    }
  }
  __syncthreads();

  // stage 2: 25-tap stencil, micro-tile 4 wide x 2 high per thread
  float acc[2][4] = {{0.f, 0.f, 0.f, 0.f}, {0.f, 0.f, 0.f, 0.f}};
  const int txi = threadIdx.x, tyi = threadIdx.y;
#pragma unroll
  for (int f = 0; f < 9; ++f) {
#pragma unroll
    for (int wr = 0; wr < 6; ++wr) {
      const int base = (2 * tyi + wr) * FCOLS + 4 * txi;  // 16B-aligned (72%4==0)
      const float4 w0 = *(const float4*)&Fp[f][base];
      const float4 w1 = *(const float4*)&Fp[f][base + 4];
      const float4 w2 = *(const float4*)&Fp[f][base + 8];
      const float w[12] = {w0.x, w0.y, w0.z, w0.w, w1.x, w1.y, w1.z, w1.w,
                           w2.x, w2.y, w2.z, w2.w};
#pragma unroll
      for (int r = 0; r < 2; ++r) {
        const int ey = wr - r;
        if (ey < 0 || ey > 4) continue;  // compile-time pruned
#pragma unroll
        for (int ex = 0; ex < 5; ++ex) {
          const float wt = Wc[f * 25 + ey * 5 + ex];  // wave-uniform -> s_load
#pragma unroll
          for (int c = 0; c < 4; ++c)
            acc[r][c] = fmaf(wt, w[c + ex + 2], acc[r][c]);
        }
      }
    }
  }

  const float rb = rbp[0];
  float* oim = out + img * HW * HW;
#pragma unroll
  for (int r = 0; r < 2; ++r) {
    int row = ty0 + 2 * tyi + r;
    float4 res = make_float4(acc[r][0] + rb, acc[r][1] + rb, acc[r][2] + rb, acc[r][3] + rb);
    *(float4*)&oim[row * HW + tx0 + 4 * txi] = res;
  }
}

// ---------------- border correction: subtract phantom T_d for p+d outside image
__global__ void kan_border(const float* __restrict__ x, const float* __restrict__ ws,
                           float* __restrict__ out) {
  int idx = blockIdx.x * 256 + threadIdx.x;
  if (idx >= NIMG * 1532) return;
  int img = idx / 1532, rem = idx % 1532;
  int pr, pc;
  if (rem < 384)      { pr = 0;              pc = rem; }
  else if (rem < 768) { pr = 383;            pc = rem - 384; }
  else if (rem < 1150){ pr = rem - 768 + 1;  pc = 0; }
  else                { pr = rem - 1150 + 1; pc = 383; }
  const float* xim = x + img * HW * HW;
  const float* h = ws + 256;
  float corr = 0.f;
#pragma unroll
  for (int dy = -1; dy <= 1; ++dy)
#pragma unroll
    for (int dx = -1; dx <= 1; ++dx) {
      int qr = pr + dy, qc = pc + dx;
      if (qr >= 0 && qr < HW && qc >= 0 && qc < HW) continue;  // valid d: no phantom
      const int d = (dy + 1) * 3 + (dx + 1);
#pragma unroll
      for (int ky = -1; ky <= 1; ++ky)
#pragma unroll
        for (int kx = -1; kx <= 1; ++kx) {
          int sr = qr + ky, sc = qc + kx;
          float v = (sr >= 0 && sr < HW && sc >= 0 && sc < HW) ? xim[sr * HW + sc] : 0.0f;
          float f[9];
          kan_feats(v, f);
          const int k = (ky + 1) * 3 + (kx + 1);
          float t = 0.f;
#pragma unroll
          for (int ft = 0; ft < 9; ++ft) t = fmaf(h[(d * 9 + k) * 9 + ft], f[ft], t);
          corr += t;
        }
    }
  out[img * HW * HW + pr * HW + pc] -= corr;
}

// ---------------- ws-free correctness fallback (only if workspace is tiny)
__global__ void kan_direct(const float* __restrict__ x, const float* __restrict__ bw,
                           const float* __restrict__ sw, const float* __restrict__ ss,
                           const float* __restrict__ rw, const float* __restrict__ rbp,
                           float* __restrict__ out) {
  int idx = blockIdx.x * 256 + threadIdx.x;
  if (idx >= NPX) return;
  int img = idx / (HW * HW), rem = idx % (HW * HW);
  int pr = rem / HW, pc = rem % HW;
  const float* xim = x + img * HW * HW;
  float acc = rbp[0];
  for (int dy = -1; dy <= 1; ++dy)
    for (int dx = -1; dx <= 1; ++dx) {
      int qr = pr + dy, qc = pc + dx;
      if (qr < 0 || qr >= HW || qc < 0 || qc >= HW) continue;
      const int d = (dy + 1) * 3 + (dx + 1);
      for (int ky = -1; ky <= 1; ++ky)
        for (int kx = -1; kx <= 1; ++kx) {
          int sr = qr + ky, sc = qc + kx;
          float v = (sr >= 0 && sr < HW && sc >= 0 && sc < HW) ? xim[sr * HW + sc] : 0.0f;
          float f[9];
          kan_feats(v, f);
          const int k = (ky + 1) * 3 + (kx + 1);
          for (int c = 0; c < 16; ++c) {
            float spl = 0.f;
            for (int b = 0; b < 8; ++b) spl = fmaf(sw[(c * 9 + k) * 8 + b], f[1 + b], spl);
            acc = fmaf(rw[c * 9 + d], fmaf(bw[c * 9 + k], f[0], ss[c * 9 + k] * spl), acc);
          }
        }
    }
  out[idx] = acc;
}

extern "C" void kernel_launch(void* const* d_in, const int* in_sizes, int n_in,
                              void* d_out, int out_size, void* d_ws, size_t ws_size,
                              hipStream_t stream) {
  const float* x  = (const float*)d_in[0];
  const float* bw = (const float*)d_in[1];
  const float* sw = (const float*)d_in[2];
  const float* ss = (const float*)d_in[3];
  const float* rw = (const float*)d_in[4];
  const float* rb = (const float*)d_in[5];
  float* out = (float*)d_out;

  if (ws_size >= 4096 && d_ws != nullptr) {
    float* ws = (float*)d_ws;
    kan_weights<<<1, 1024, 0, stream>>>(bw, sw, ss, rw, ws);
    dim3 grid(HW / TW, HW / TH, NIMG), blk(16, 8);
    kan_main<<<grid, blk, 0, stream>>>(x, ws, rb, out);
    kan_border<<<(NIMG * 1532 + 255) / 256, 256, 0, stream>>>(x, ws, out);
  } else {
    kan_direct<<<(NPX + 255) / 256, 256, 0, stream>>>(x, bw, sw, ss, rw, rb, out);
  }
}